// Round 6
// baseline (683.970 us; speedup 1.0000x reference)
//
#include <hip/hip_runtime.h>
#include <cmath>

// LinearGaussianChain v7: fuse k_fix into k_pack (k_packfix).
//  - k_fix's 252MB xtemp RMW eliminated: corr = P_t * h_c is recomputed
//    inside the pack kernel via MFMA (block = 16 m-rows x 32 n x 64 t, so
//    Pf/hA reads amortize over 16 m-rows; hA is already in 16-row A-frag
//    granularity from k_phase2).
//  - per 16-t chunk group: preload x/eps vectors, corr MFMA + SWB restage
//    (v6 k_fix pattern, wave-private + fences), m = x - s*e, stage into
//    512x17 LDS transpose buffer, flush x then m (mv held in regs) as
//    64B-segment stores (L2 merges adjacent chunk flushes into full lines).
//  - 43KB LDS -> 2 blocks/CU.
// x-temp (uncorrected zero-start chains) lives in the s-output third of
// d_out; k_s overwrites it last.

typedef __bf16 bf16x8 __attribute__((ext_vector_type(8)));
typedef float f32x4 __attribute__((ext_vector_type(4)));

#define XB_STRIDE 144  // bytes per LDS row: 64 bf16 + 16B pad

// [16 rows][64 cols] f32 stage (k_phase1): row XOR breaks stride-64 aliasing.
#define SWA(row, col) ((row)*64 + ((col) ^ ((((row)) & 7) << 2)))
// [16 rows][32 cols] f32 corr stage (k_packfix). Bijective per row: xor<32.
#define SWB(row, col) ((row)*32 + ((col) ^ ((((row)) & 7) << 2)))

__device__ __forceinline__ float softplus_f(float z) {
  return (z > 20.0f) ? z : log1pf(expf(z));
}

// ---- k_wf: repack W (T,64,64) fp32 -> bf16 B-frag order; build s tables ----
// Wf entry ((t*4+nt)*2+kh)*64+lane, lane=(q<<4)|n15 holds W[t][16nt+n15][32kh+8q+j]
__global__ void k_wf(const float* __restrict__ W, const float* __restrict__ ne,
                     bf16x8* __restrict__ Wf, float* __restrict__ st,
                     float* __restrict__ stT) {
  int t = blockIdx.x;
  for (int e = threadIdx.x; e < 512; e += blockDim.x) {
    int lane = e & 63;
    int kh = (e >> 6) & 1;
    int nt = e >> 7;
    int q = lane >> 4, n15 = lane & 15;
    int n = nt * 16 + n15;
    int k0 = kh * 32 + q * 8;
    const float* src = W + ((size_t)t * 64 + n) * 64 + k0;
    bf16x8 v;
#pragma unroll
    for (int j = 0; j < 8; ++j) v[j] = (__bf16)src[j];
    Wf[((size_t)(t * 4 + nt) * 2 + kh) * 64 + lane] = v;
  }
  if (threadIdx.x < 64) {
    int n = threadIdx.x;
    float v = (t == 0) ? 1.0f : softplus_f(ne[n * 256 + t]);
    st[n * 256 + t] = v;
    stT[t * 64 + n] = v;
  }
}

// ---- k_prefix: chunk c=b+1, P_t = W_t * P_{t-1}, P starts at W_{16c}.
// Track Q = P^T (Q <- Q @ W_t^T), dump B-frags of P after every step. ----
__global__ __launch_bounds__(256) void k_prefix(const bf16x8* __restrict__ Wf,
                                                bf16x8* __restrict__ Pf) {
  __shared__ __align__(16) unsigned char Q[64 * XB_STRIDE];
  int b = blockIdx.x;  // 0..14, chunk c = b+1
  int c = b + 1;
  int tid = threadIdx.x;
  int lane = tid & 63, w = tid >> 6;
  int q = lane >> 4, n15 = lane & 15;
  int rbase = w * 16;
  for (int e = tid; e < 4096; e += 256) {
    int r = e >> 6, k = e & 63;
    *(__bf16*)(Q + r * XB_STRIDE + k * 2) = (__bf16)((r == k) ? 1.0f : 0.0f);
  }
  __syncthreads();
  for (int tl = 0; tl < 16; ++tl) {
    int t = c * 16 + tl;
    bf16x8 a0 = *(const bf16x8*)(Q + (rbase + n15) * XB_STRIDE + q * 16);
    bf16x8 a1 = *(const bf16x8*)(Q + (rbase + n15) * XB_STRIDE + 64 + q * 16);
    f32x4 acc[4];
#pragma unroll
    for (int nt = 0; nt < 4; ++nt) {
      bf16x8 b0 = Wf[((size_t)(t * 4 + nt) * 2 + 0) * 64 + lane];
      bf16x8 b1 = Wf[((size_t)(t * 4 + nt) * 2 + 1) * 64 + lane];
      f32x4 z = {0.f, 0.f, 0.f, 0.f};
      z = __builtin_amdgcn_mfma_f32_16x16x32_bf16(a0, b0, z, 0, 0, 0);
      z = __builtin_amdgcn_mfma_f32_16x16x32_bf16(a1, b1, z, 0, 0, 0);
      acc[nt] = z;
    }
#pragma unroll
    for (int nt = 0; nt < 4; ++nt)
#pragma unroll
      for (int reg = 0; reg < 4; ++reg)
        *(__bf16*)(Q + (rbase + 4 * q + reg) * XB_STRIDE + (nt * 16 + n15) * 2) =
            (__bf16)acc[nt][reg];
    __syncthreads();  // all rows updated before dump
    for (int e = tid; e < 512; e += 256) {
      int lane2 = e & 63;
      int kh = (e >> 6) & 1;
      int nt = e >> 7;
      int q2 = lane2 >> 4;
      int nn = nt * 16 + (lane2 & 15);
      bf16x8 v;
#pragma unroll
      for (int j = 0; j < 8; ++j)
        v[j] = *(const __bf16*)(Q + (kh * 32 + q2 * 8 + j) * XB_STRIDE + nn * 2);
      Pf[((size_t)(b * 16 + tl) * 8 + nt * 2 + kh) * 64 + lane2] = v;
    }
    __syncthreads();  // dump done before next overwrite
  }
}

// ---- k_phase1: zero-start chunk chains, x-temp t-major. 4 indep waves/block.
// xtemp stores restaged through swizzled LDS -> 4x 1KB dwordx4 per step.
__global__ __launch_bounds__(256) void k_phase1(
    const float* __restrict__ bb, const float* __restrict__ st,
    const float* __restrict__ eps0, const float* __restrict__ eps,
    const bf16x8* __restrict__ Wf, float* __restrict__ xtemp) {
  __shared__ float stab[16][64];
  __shared__ float btab[16][64];
  __shared__ __align__(16) unsigned char xball[4 * 16 * XB_STRIDE];
  __shared__ __align__(16) float xstage[4][16 * 64];
  int tid = threadIdx.x, w = tid >> 6, lane = tid & 63;
  unsigned char* xb = xball + w * 16 * XB_STRIDE;
  float* xs = xstage[w];
  int c = blockIdx.x >> 5;                     // 0..15
  int r0 = ((blockIdx.x & 31) * 4 + w) * 16;   // 16-row tile
  int q = lane >> 4, n15 = lane & 15;
  for (int e = tid; e < 1024; e += 256) {
    int tl = e >> 6, n = e & 63, t = c * 16 + tl;
    stab[tl][n] = st[n * 256 + t];
    btab[tl][n] = bb[t * 64 + n];
  }
  if (c == 0) {
    for (int i = 0; i < 16; ++i) {
      float v = eps0[(size_t)(r0 + i) * 64 + lane];
      *(__bf16*)(xb + i * XB_STRIDE + lane * 2) = (__bf16)v;
      xtemp[((size_t)(r0 + i)) * 64 + lane] = v;  // t=0
    }
  } else {
    for (int i = 0; i < 16; ++i)
      *(__bf16*)(xb + i * XB_STRIDE + lane * 2) = (__bf16)0.0f;
  }
  __syncthreads();  // stab/btab ready
  int t0 = (c == 0) ? 1 : c * 16;
  int t1 = c * 16 + 15;
  float epc[16], epn[16];
#pragma unroll
  for (int nt = 0; nt < 4; ++nt)
#pragma unroll
    for (int reg = 0; reg < 4; ++reg)
      epc[nt * 4 + reg] =
          eps[((size_t)(t0 - 1) * 2048 + r0 + 4 * q + reg) * 64 + nt * 16 + n15];
  for (int t = t0; t <= t1; ++t) {
    bool more = (t < t1);
    if (more) {
#pragma unroll
      for (int nt = 0; nt < 4; ++nt)
#pragma unroll
        for (int reg = 0; reg < 4; ++reg)
          epn[nt * 4 + reg] =
              eps[((size_t)t * 2048 + r0 + 4 * q + reg) * 64 + nt * 16 + n15];
    }
    bf16x8 a0 = *(const bf16x8*)(xb + n15 * XB_STRIDE + q * 16);
    bf16x8 a1 = *(const bf16x8*)(xb + n15 * XB_STRIDE + 64 + q * 16);
    f32x4 acc[4];
#pragma unroll
    for (int nt = 0; nt < 4; ++nt) {
      bf16x8 b0 = Wf[((size_t)(t * 4 + nt) * 2 + 0) * 64 + lane];
      bf16x8 b1 = Wf[((size_t)(t * 4 + nt) * 2 + 1) * 64 + lane];
      f32x4 z = {0.f, 0.f, 0.f, 0.f};
      z = __builtin_amdgcn_mfma_f32_16x16x32_bf16(a0, b0, z, 0, 0, 0);
      z = __builtin_amdgcn_mfma_f32_16x16x32_bf16(a1, b1, z, 0, 0, 0);
      acc[nt] = z;
    }
    int tl = t - c * 16;
#pragma unroll
    for (int nt = 0; nt < 4; ++nt) {
      int n = nt * 16 + n15;
      float sv = stab[tl][n];
      float bv = btab[tl][n];
#pragma unroll
      for (int reg = 0; reg < 4; ++reg) {
        int row = 4 * q + reg;
        float xn = acc[nt][reg] + bv + sv * epc[nt * 4 + reg];
        xs[SWA(row, n)] = xn;
        *(__bf16*)(xb + row * XB_STRIDE + n * 2) = (__bf16)xn;
      }
    }
    asm volatile("" ::: "memory");  // stage writes ordered before flush reads
    {
      size_t basef = ((size_t)t * 2048 + r0) * 64 + 4 * lane;
#pragma unroll
      for (int k = 0; k < 4; ++k) {
        int rr = 4 * k + (lane >> 4);
        int cc = 4 * (lane & 15);
        f32x4 v;
#pragma unroll
        for (int j = 0; j < 4; ++j) v[j] = xs[SWA(rr, cc + j)];
        *(f32x4*)(xtemp + basef + 256 * k) = v;
      }
    }
    asm volatile("" ::: "memory");  // flush reads ordered before next writes
    if (more) {
#pragma unroll
      for (int i = 0; i < 16; ++i) epc[i] = epn[i];
    }
  }
}

// ---- k_phase2: h_1 = x_15; h_{c+1} = tail_c + M_c h_c. Dumps bf16 A-frags
// hA[c] for c=1..15 (exactly the frags k_packfix consumes). ----
__global__ __launch_bounds__(256) void k_phase2(const bf16x8* __restrict__ Pf,
                                                const float* __restrict__ xtemp,
                                                bf16x8* __restrict__ hA) {
  __shared__ __align__(16) unsigned char hball[4 * 16 * XB_STRIDE];
  int tid = threadIdx.x, w = tid >> 6, lane = tid & 63;
  unsigned char* hb = hball + w * 16 * XB_STRIDE;
  int rtile = blockIdx.x * 4 + w;  // 0..127
  int r0 = rtile * 16;
  int q = lane >> 4, n15 = lane & 15;
  for (int i = 0; i < 16; ++i) {
    float v = xtemp[((size_t)15 * 2048 + r0 + i) * 64 + lane];
    *(__bf16*)(hb + i * XB_STRIDE + lane * 2) = (__bf16)v;
  }
  for (int c = 1; c <= 15; ++c) {
    bf16x8 a0 = *(const bf16x8*)(hb + n15 * XB_STRIDE + q * 16);
    bf16x8 a1 = *(const bf16x8*)(hb + n15 * XB_STRIDE + 64 + q * 16);
    size_t hbase = ((size_t)(c - 1) * 128 + rtile) * 128;
    hA[hbase + lane] = a0;
    hA[hbase + 64 + lane] = a1;
    if (c == 15) break;
    f32x4 acc[4];
#pragma unroll
    for (int nt = 0; nt < 4; ++nt) {
      bf16x8 b0 = Pf[((size_t)((c - 1) * 16 + 15) * 8 + nt * 2 + 0) * 64 + lane];
      bf16x8 b1 = Pf[((size_t)((c - 1) * 16 + 15) * 8 + nt * 2 + 1) * 64 + lane];
      f32x4 z = {0.f, 0.f, 0.f, 0.f};
      z = __builtin_amdgcn_mfma_f32_16x16x32_bf16(a0, b0, z, 0, 0, 0);
      z = __builtin_amdgcn_mfma_f32_16x16x32_bf16(a1, b1, z, 0, 0, 0);
      acc[nt] = z;
    }
#pragma unroll
    for (int nt = 0; nt < 4; ++nt) {
      int n = nt * 16 + n15;
#pragma unroll
      for (int reg = 0; reg < 4; ++reg) {
        int row = 4 * q + reg;
        float tail = xtemp[((size_t)(16 * c + 15) * 2048 + r0 + row) * 64 + n];
        float hn = acc[nt][reg] + tail;
        *(__bf16*)(hb + row * XB_STRIDE + n * 2) = (__bf16)hn;
      }
    }
  }
}

// ---- k_packfix: fused fix+pack. Block = 16 m-rows x 32 n x 64 t.
// grid: bid = (tq*2 + nh)*128 + mtile  (1024 blocks).
// Per chunk group (16 t): corr = P_t * h_c via MFMA (c>0), x = xtemp + corr,
// m = x - s*e; transpose-stage [512 rows = mi*32+nl][16 i-cols] (stride 17),
// flush x then m (m held in regs) as 64B-per-row f32x4 stores.
__global__ __launch_bounds__(256) void k_packfix(
    const bf16x8* __restrict__ Pf, const bf16x8* __restrict__ hA,
    const float* __restrict__ stT, const float* __restrict__ eps0,
    const float* __restrict__ eps, const float* __restrict__ xtemp,
    float* __restrict__ out) {
  __shared__ float stg[512 * 17];  // 34KB transpose stage (x, then m)
  __shared__ float cwb[4][512];    // per-wave 16x32 corr restage (SWB)
  const size_t MSOFF = (size_t)2048 * 64 * 256;
  int tid = threadIdx.x, w = tid >> 6, lane = tid & 63;
  int mtile = blockIdx.x & 127;
  int nh = (blockIdx.x >> 7) & 1;
  int tq = blockIdx.x >> 8;  // 0..3
  int mm0 = mtile * 16;
  int rr0 = lane & 7;         // tile m-row (and +8)
  int cc = 4 * (lane >> 3);   // local n quad 0..28
  int q = lane >> 4, n15 = lane & 15;
  float* cw = cwb[w];
  const f32x4 zv = {0.f, 0.f, 0.f, 0.f};
  int frow = tid >> 2, fcq = (tid & 3) * 4;
  for (int g = 0; g < 4; ++g) {
    int c = tq * 4 + g;   // chunk index = t>>4 for this group
    int tb = c * 16;
    bf16x8 a0, a1;
    if (c > 0) {
      size_t hbase = ((size_t)(c - 1) * 128 + mtile) * 128;
      a0 = hA[hbase + lane];
      a1 = hA[hbase + 64 + lane];
    }
    // preload x/eps vectors for this wave's 4 t's (hide HBM latency)
    f32x4 xv[4][2], ev[4][2];
#pragma unroll
    for (int j = 0; j < 4; ++j) {
      int t = tb + w * 4 + j;
#pragma unroll
      for (int k = 0; k < 2; ++k) {
        int row = mm0 + rr0 + 8 * k;
        xv[j][k] =
            *(const f32x4*)(xtemp + ((size_t)t * 2048 + row) * 64 + nh * 32 + cc);
        const float* ep = (t == 0) ? (eps0 + (size_t)row * 64)
                                   : (eps + ((size_t)(t - 1) * 2048 + row) * 64);
        ev[j][k] = *(const f32x4*)(ep + nh * 32 + cc);
      }
    }
    f32x4 mv[4][2];
#pragma unroll
    for (int j = 0; j < 4; ++j) {
      int tl = w * 4 + j;
      int t = tb + tl;
      f32x4 cv[2];
      cv[0] = zv;
      cv[1] = zv;
      if (c > 0) {
#pragma unroll
        for (int ntl = 0; ntl < 2; ++ntl) {
          bf16x8 b0 =
              Pf[((size_t)((c - 1) * 16 + tl) * 8 + (2 * nh + ntl) * 2 + 0) * 64 +
                 lane];
          bf16x8 b1 =
              Pf[((size_t)((c - 1) * 16 + tl) * 8 + (2 * nh + ntl) * 2 + 1) * 64 +
                 lane];
          f32x4 z = {0.f, 0.f, 0.f, 0.f};
          z = __builtin_amdgcn_mfma_f32_16x16x32_bf16(a0, b0, z, 0, 0, 0);
          z = __builtin_amdgcn_mfma_f32_16x16x32_bf16(a1, b1, z, 0, 0, 0);
          // stage C-layout -> vector layout (rows 4q+reg, cols ntl*16+n15)
#pragma unroll
          for (int reg = 0; reg < 4; ++reg)
            cw[SWB(4 * q + reg, ntl * 16 + n15)] = z[reg];
        }
        asm volatile("" ::: "memory");  // stage writes before reads
#pragma unroll
        for (int k = 0; k < 2; ++k)
#pragma unroll
          for (int jj = 0; jj < 4; ++jj)
            cv[k][jj] = cw[SWB(rr0 + 8 * k, cc + jj)];
        asm volatile("" ::: "memory");  // reads before next j's writes
      }
      f32x4 sv = *(const f32x4*)(stT + (size_t)t * 64 + nh * 32 + cc);
      int colt = 15 - tl;  // i = ib0 + colt
#pragma unroll
      for (int k = 0; k < 2; ++k) {
        f32x4 xf = xv[j][k] + cv[k];
        mv[j][k] = xf - sv * ev[j][k];
#pragma unroll
        for (int jj = 0; jj < 4; ++jj)
          stg[((rr0 + 8 * k) * 32 + cc + jj) * 17 + colt] = xf[jj];
      }
    }
    __syncthreads();  // all x staged
    int ib0 = 240 - 16 * c;
#pragma unroll
    for (int it = 0; it < 8; ++it) {
      int row = frow + 64 * it;  // 0..511 = mi*32 + nl
      int mi = row >> 5, nl = row & 31;
      size_t ob = ((size_t)(mm0 + mi) * 64 + nh * 32 + nl) * 256 + ib0 + fcq;
      f32x4 v;
#pragma unroll
      for (int jj = 0; jj < 4; ++jj) v[jj] = stg[row * 17 + fcq + jj];
      *(f32x4*)(out + ob) = v;
    }
    __syncthreads();  // x flushed before m overwrites stage
#pragma unroll
    for (int j = 0; j < 4; ++j) {
      int colt = 15 - (w * 4 + j);
#pragma unroll
      for (int k = 0; k < 2; ++k)
#pragma unroll
        for (int jj = 0; jj < 4; ++jj)
          stg[((rr0 + 8 * k) * 32 + cc + jj) * 17 + colt] = mv[j][k][jj];
    }
    __syncthreads();  // all m staged
#pragma unroll
    for (int it = 0; it < 8; ++it) {
      int row = frow + 64 * it;
      int mi = row >> 5, nl = row & 31;
      size_t ob =
          MSOFF + ((size_t)(mm0 + mi) * 64 + nh * 32 + nl) * 256 + ib0 + fcq;
      f32x4 v;
#pragma unroll
      for (int jj = 0; jj < 4; ++jj) v[jj] = stg[row * 17 + fcq + jj];
      *(f32x4*)(out + ob) = v;
    }
    __syncthreads();  // m flushed before next group's stage
  }
}

// ---- k_s: s output = table broadcast over m, t-flipped ----
__global__ __launch_bounds__(256) void k_s(const float* __restrict__ st,
                                           float* __restrict__ out) {
  int gid = blockIdx.x * 256 + threadIdx.x;  // 0..8388607
  int i0 = (gid & 63) * 4;
  int n = (gid >> 6) & 63;
  int m = gid >> 12;
  const float4 rv = *(const float4*)(st + n * 256 + 252 - i0);
  f32x4 v = {rv.w, rv.z, rv.y, rv.x};
  *(f32x4*)(out + (size_t)2 * 2048 * 64 * 256 + ((size_t)m * 64 + n) * 256 + i0) = v;
}

extern "C" void kernel_launch(void* const* d_in, const int* in_sizes, int n_in,
                              void* d_out, int out_size, void* d_ws, size_t ws_size,
                              hipStream_t stream) {
  const float* W = (const float*)d_in[0];     // (256,64,64)
  const float* bb = (const float*)d_in[1];    // (256,64)
  const float* ne = (const float*)d_in[2];    // (1,64,256)
  const float* eps0 = (const float*)d_in[3];  // (2048,64)
  const float* eps = (const float*)d_in[4];   // (255,2048,64)
  float* out = (float*)d_out;
  char* ws = (char*)d_ws;
  // ws layout: Wf 2MB | st 128KB | stT 128KB | Pf 2MB | hA 4MB  (~8.25 MB)
  bf16x8* Wf = (bf16x8*)ws;
  float* st = (float*)(ws + (size_t)(2u << 20));
  float* stT = (float*)(ws + (size_t)(2u << 20) + (128u << 10));
  bf16x8* Pf = (bf16x8*)(ws + (size_t)(2u << 20) + (256u << 10));
  bf16x8* hA = (bf16x8*)(ws + (size_t)(4u << 20) + (256u << 10));
  // x-temp (t-major, 134MB) lives in the s-output third of d_out.
  float* xtemp = out + (size_t)2 * 2048 * 64 * 256;

  hipLaunchKernelGGL(k_wf, dim3(256), dim3(256), 0, stream, W, ne, Wf, st, stT);
  hipLaunchKernelGGL(k_prefix, dim3(15), dim3(256), 0, stream, Wf, Pf);
  hipLaunchKernelGGL(k_phase1, dim3(512), dim3(256), 0, stream, bb, st, eps0, eps, Wf, xtemp);
  hipLaunchKernelGGL(k_phase2, dim3(32), dim3(256), 0, stream, Pf, xtemp, hA);
  hipLaunchKernelGGL(k_packfix, dim3(1024), dim3(256), 0, stream, Pf, hA, stT, eps0, eps, xtemp, out);
  hipLaunchKernelGGL(k_s, dim3(32768), dim3(256), 0, stream, st, out);
}